// Round 1
// baseline (10277.758 us; speedup 1.0000x reference)
//
#include <hip/hip_runtime.h>
#include <cstdint>
#include <cstddef>

// Problem constants
#define BB 32
#define TT 2048
#define DD 256
#define HH 256
#define CC 128
#define GG 512   // 2*H

// ---------- bf16 helpers ----------
#if defined(__has_builtin)
#  if __has_builtin(__builtin_amdgcn_fdot2_f32_bf16)
#    define HAVE_BF16_DOT2 1
#  endif
#endif
#ifndef HAVE_BF16_DOT2
#  define HAVE_BF16_DOT2 0
#endif

#if HAVE_BF16_DOT2
typedef __bf16 bf16x2_t __attribute__((ext_vector_type(2)));
#endif

__device__ __forceinline__ float bflo(uint32_t w) { return __uint_as_float(w << 16); }
__device__ __forceinline__ float bfhi(uint32_t w) { return __uint_as_float(w & 0xffff0000u); }

// dot2: acc += lo(w)*lo(h) + hi(w)*hi(h), f32 accumulate
__device__ __forceinline__ float dot2bf(uint32_t w, uint32_t h, float acc) {
#if HAVE_BF16_DOT2
  return __builtin_amdgcn_fdot2_f32_bf16(__builtin_bit_cast(bf16x2_t, w),
                                         __builtin_bit_cast(bf16x2_t, h),
                                         acc, false);
#else
  acc = fmaf(bflo(w), bflo(h), acc);
  acc = fmaf(bfhi(w), bfhi(h), acc);
  return acc;
#endif
}

// round-to-nearest-even f32 -> bf16 bits
__device__ __forceinline__ uint16_t f2bf(float x) {
  uint32_t u = __float_as_uint(x);
  uint32_t r = (u + 0x7fffu + ((u >> 16) & 1u)) >> 16;
  return (uint16_t)r;
}

__device__ __forceinline__ uint32_t pkbf(float a, float b) {
  return (uint32_t)f2bf(a) | ((uint32_t)f2bf(b) << 16);
}

// ---------- K0: prep (pack combined Wx, bias, and bf16 k-pair-packed recurrent weights) ----------
// Whg2[k2*512 + j]  = pack(Wh_g[2k2][j],  Wh_g[2k2+1][j])
// Whc2[k2*256 + j]  = pack(Wh_c[2k2][j],  Wh_c[2k2+1][j])
// Wp2 [k2*128 + j]  = pack(W_proj[2k2][j],W_proj[2k2+1][j])
__global__ void prep_kernel(const float* __restrict__ Wg, const float* __restrict__ bg,
                            const float* __restrict__ Wc, const float* __restrict__ bc,
                            const float* __restrict__ Wp,
                            float* __restrict__ Bm, float* __restrict__ bias,
                            uint32_t* __restrict__ Whg2, uint32_t* __restrict__ Whc2,
                            uint32_t* __restrict__ Wp2) {
  int i = blockIdx.x * 256 + threadIdx.x;
  if (i < 196608) {                       // Bm: [256][768] combined input weights
    int k = i / 768, n = i % 768;
    Bm[i] = (n < GG) ? Wg[k * GG + n] : Wc[k * HH + (n - GG)];
    return;
  }
  int j = i - 196608;
  if (j < 768) {                          // bias[768]
    bias[j] = (j < GG) ? bg[j] : bc[j - GG];
    return;
  }
  int a = i - 197376;
  if (a < 65536) {                        // Whg2
    int k2 = a >> 9, jj = a & 511;
    Whg2[a] = pkbf(Wg[(DD + 2 * k2) * GG + jj], Wg[(DD + 2 * k2 + 1) * GG + jj]);
    return;
  }
  int c2 = i - 262912;
  if (c2 < 32768) {                       // Whc2
    int k2 = c2 >> 8, jj = c2 & 255;
    Whc2[c2] = pkbf(Wc[(DD + 2 * k2) * HH + jj], Wc[(DD + 2 * k2 + 1) * HH + jj]);
    return;
  }
  int p2 = i - 295680;
  if (p2 < 16384) {                       // Wp2
    int k2 = p2 >> 7, jj = p2 & 127;
    Wp2[p2] = pkbf(Wp[(2 * k2) * CC + jj], Wp[(2 * k2 + 1) * CC + jj]);
  }
}

// ---------- K1: input GEMM  gxc[65536][768] = x[65536][256] @ Bm[256][768] + bias ----------
__global__ __launch_bounds__(256) void gemm_in(const float* __restrict__ A,
                                               const float* __restrict__ Bm,
                                               const float* __restrict__ bias,
                                               float* __restrict__ Cm) {
  __shared__ __align__(16) float As[16][65];   // [k][m], padded
  __shared__ __align__(16) float Bs[16][64];   // [k][n]
  const int tidx = threadIdx.x;
  const int tx = tidx & 15;   // n-group
  const int ty = tidx >> 4;   // m-group
  const int m0 = blockIdx.y * 64;
  const int n0 = blockIdx.x * 64;
  float acc[4][4] = {};

  for (int k0 = 0; k0 < DD; k0 += 16) {
    {
      int r = tidx >> 2;
      int c = (tidx & 3) * 4;
      float4 av = *(const float4*)(A + (size_t)(m0 + r) * DD + k0 + c);
      As[c + 0][r] = av.x; As[c + 1][r] = av.y; As[c + 2][r] = av.z; As[c + 3][r] = av.w;
    }
    {
      int r = tidx >> 6;          // 0..3
      int cc = tidx & 63;
      #pragma unroll
      for (int i = 0; i < 4; i++)
        Bs[r + i * 4][cc] = Bm[(size_t)(k0 + r + i * 4) * 768 + n0 + cc];
    }
    __syncthreads();
    #pragma unroll
    for (int kk = 0; kk < 16; kk++) {
      float a[4], bb[4];
      #pragma unroll
      for (int i = 0; i < 4; i++) a[i] = As[kk][ty * 4 + i];
      #pragma unroll
      for (int jj = 0; jj < 4; jj++) bb[jj] = Bs[kk][tx * 4 + jj];
      #pragma unroll
      for (int i = 0; i < 4; i++)
        #pragma unroll
        for (int jj = 0; jj < 4; jj++)
          acc[i][jj] = fmaf(a[i], bb[jj], acc[i][jj]);
    }
    __syncthreads();
  }
  float4 bv = *(const float4*)&bias[n0 + tx * 4];
  #pragma unroll
  for (int i = 0; i < 4; i++) {
    int m = m0 + ty * 4 + i;
    float4 o;
    o.x = acc[i][0] + bv.x; o.y = acc[i][1] + bv.y;
    o.z = acc[i][2] + bv.z; o.w = acc[i][3] + bv.w;
    *(float4*)(Cm + (size_t)m * 768 + n0 + tx * 4) = o;
  }
}

// ---------- K2: sequential scan, one workgroup per batch element, fused out-projection ----------
__global__ __launch_bounds__(512) void rnn_scan(const float* __restrict__ gxc,
                                                const uint32_t* __restrict__ Whg2,
                                                const uint32_t* __restrict__ Whc2,
                                                const uint32_t* __restrict__ Wp2,
                                                const float* __restrict__ bproj,
                                                float* __restrict__ out) {
  __shared__ __align__(16) float    s_hf[HH];     // h, f32
  __shared__ __align__(16) uint32_t s_h2[HH / 2]; // h, packed bf16 pairs (k-pairs)
  __shared__ __align__(16) float    s_g[GG];      // gates (r | u)
  __shared__ __align__(16) uint32_t s_rh2[HH / 2];// r*h packed bf16 pairs
  __shared__ __align__(16) float    s_p[512];     // partials

  const int tid = threadIdx.x;
  const int b = blockIdx.x;

  if (tid < HH) s_hf[tid] = 0.f;
  if (tid < HH / 2) s_h2[tid] = 0u;
  __syncthreads();

  const float* gx_b = gxc + (size_t)b * TT * 768;
  float* out_b = out + (size_t)b * TT * CC;

  for (int t = 0; t < TT; t++) {
    const float* gx_t = gx_b + (size_t)t * 768;

    // ---- phase 1: gates = sigmoid(gx + h @ Wh_g); thread j owns gate j (full k) ----
    {
      float acc = gx_t[tid];
      const uint32_t* wp = Whg2 + tid;
      #pragma unroll 4
      for (int k2 = 0; k2 < 128; k2 += 4) {
        uint4 hh = *(const uint4*)&s_h2[k2];
        acc = dot2bf(wp[(k2 + 0) * 512], hh.x, acc);
        acc = dot2bf(wp[(k2 + 1) * 512], hh.y, acc);
        acc = dot2bf(wp[(k2 + 2) * 512], hh.z, acc);
        acc = dot2bf(wp[(k2 + 3) * 512], hh.w, acc);
      }
      s_g[tid] = 1.f / (1.f + __expf(-acc));
    }
    __syncthreads();  // A: s_g ready

    // ---- phase 1.5: rh = r * h, packed bf16 ----
    if (tid < HH) {
      float v = s_g[tid] * s_hf[tid];
      ((uint16_t*)s_rh2)[tid] = f2bf(v);
    }
    __syncthreads();  // B: s_rh2 ready

    // ---- phase 2: cand partials; thread (jc, kh) does half the k range ----
    {
      int jc = tid & 255, kh = tid >> 8;
      float acc = 0.f;
      const uint32_t* wp = Whc2 + jc;
      int k2b = kh * 64;
      #pragma unroll 4
      for (int k2 = k2b; k2 < k2b + 64; k2 += 4) {
        uint4 rr = *(const uint4*)&s_rh2[k2];
        acc = dot2bf(wp[(k2 + 0) * 256], rr.x, acc);
        acc = dot2bf(wp[(k2 + 1) * 256], rr.y, acc);
        acc = dot2bf(wp[(k2 + 2) * 256], rr.z, acc);
        acc = dot2bf(wp[(k2 + 3) * 256], rr.w, acc);
      }
      s_p[kh * 256 + jc] = acc;
    }
    __syncthreads();  // C: partials ready

    // ---- combine: c = tanh(cx + p0 + p1); h = u*h + (1-u)*c ----
    if (tid < HH) {
      float pre = gx_t[GG + tid] + s_p[tid] + s_p[256 + tid];
      float e = __expf(-2.f * fabsf(pre));
      float tm = (1.f - e) / (1.f + e);
      float c = copysignf(tm, pre);
      float u = s_g[HH + tid];
      float hf = s_hf[tid];
      float hn = u * hf + (1.f - u) * c;
      s_hf[tid] = hn;
      ((uint16_t*)s_h2)[tid] = f2bf(hn);
    }
    __syncthreads();  // D: new h ready

    // ---- phase 3: out partials; thread (j3, q) does quarter k range ----
    {
      int j3 = tid & 127, q = tid >> 7;
      float acc = 0.f;
      const uint32_t* wp = Wp2 + j3;
      int k2b = q * 32;
      #pragma unroll 4
      for (int k2 = k2b; k2 < k2b + 32; k2 += 4) {
        uint4 hh = *(const uint4*)&s_h2[k2];
        acc = dot2bf(wp[(k2 + 0) * 128], hh.x, acc);
        acc = dot2bf(wp[(k2 + 1) * 128], hh.y, acc);
        acc = dot2bf(wp[(k2 + 2) * 128], hh.z, acc);
        acc = dot2bf(wp[(k2 + 3) * 128], hh.w, acc);
      }
      s_p[q * 128 + j3] = acc;
    }
    __syncthreads();  // E: out partials ready

    if (tid < CC) {
      float pre = bproj[tid] + s_p[tid] + s_p[128 + tid] + s_p[256 + tid] + s_p[384 + tid];
      out_b[(size_t)t * CC + tid] = 1.f / (1.f + __expf(-pre));
    }
    // next phase-2 write of s_p is fenced by barriers A/B of the next iteration
  }
}

// ---------- launch ----------
extern "C" void kernel_launch(void* const* d_in, const int* in_sizes, int n_in,
                              void* d_out, int out_size, void* d_ws, size_t ws_size,
                              hipStream_t stream) {
  const float* x  = (const float*)d_in[0];
  const float* Wg = (const float*)d_in[1];
  const float* bg = (const float*)d_in[2];
  const float* Wc = (const float*)d_in[3];
  const float* bc = (const float*)d_in[4];
  const float* Wp = (const float*)d_in[5];
  const float* bp = (const float*)d_in[6];
  float* out = (float*)d_out;

  // workspace carve (bytes)
  char* w = (char*)d_ws;
  float*    gxc  = (float*)   (w);                  // 32*2048*768*4   = 201326592
  float*    Bm   = (float*)   (w + 201326592ull);   // 256*768*4       = 786432
  float*    bias = (float*)   (w + 202113024ull);   // 768*4           = 3072
  uint32_t* Whg2 = (uint32_t*)(w + 202116096ull);   // 128*512*4       = 262144
  uint32_t* Whc2 = (uint32_t*)(w + 202378240ull);   // 128*256*4       = 131072
  uint32_t* Wp2  = (uint32_t*)(w + 202509312ull);   // 128*128*4       = 65536
                                                    // total           = 202574848 B

  prep_kernel<<<1219, 256, 0, stream>>>(Wg, bg, Wc, bc, Wp, Bm, bias, Whg2, Whc2, Wp2);
  gemm_in<<<dim3(12, 1024), 256, 0, stream>>>(x, Bm, bias, gxc);
  rnn_scan<<<BB, 512, 0, stream>>>(gxc, Whg2, Whc2, Wp2, bp, out);
}

// Round 2
// 3890.533 us; speedup vs baseline: 2.6417x; 2.6417x over previous
//
#include <hip/hip_runtime.h>
#include <cstdint>
#include <cstddef>

// Problem constants
#define BB 32
#define TT 2048
#define DD 256
#define HH 256
#define CC 128
#define GG 512   // 2*H

// ---------- bf16 helpers ----------
#if defined(__has_builtin)
#  if __has_builtin(__builtin_amdgcn_fdot2_f32_bf16)
#    define HAVE_BF16_DOT2 1
#  endif
#endif
#ifndef HAVE_BF16_DOT2
#  define HAVE_BF16_DOT2 0
#endif

#if HAVE_BF16_DOT2
typedef __bf16 bf16x2_t __attribute__((ext_vector_type(2)));
#endif

__device__ __forceinline__ float bflo(uint32_t w) { return __uint_as_float(w << 16); }
__device__ __forceinline__ float bfhi(uint32_t w) { return __uint_as_float(w & 0xffff0000u); }

__device__ __forceinline__ float dot2bf(uint32_t w, uint32_t h, float acc) {
#if HAVE_BF16_DOT2
  return __builtin_amdgcn_fdot2_f32_bf16(__builtin_bit_cast(bf16x2_t, w),
                                         __builtin_bit_cast(bf16x2_t, h),
                                         acc, false);
#else
  acc = fmaf(bflo(w), bflo(h), acc);
  acc = fmaf(bfhi(w), bfhi(h), acc);
  return acc;
#endif
}

// round-to-nearest-even f32 -> bf16 bits
__device__ __forceinline__ uint16_t f2bf(float x) {
  uint32_t u = __float_as_uint(x);
  uint32_t r = (u + 0x7fffu + ((u >> 16) & 1u)) >> 16;
  return (uint16_t)r;
}

__device__ __forceinline__ uint32_t pkbf(float a, float b) {
  return (uint32_t)f2bf(a) | ((uint32_t)f2bf(b) << 16);
}

// ---------- K0: prep ----------
__global__ void prep_kernel(const float* __restrict__ Wg, const float* __restrict__ bg,
                            const float* __restrict__ Wc, const float* __restrict__ bc,
                            const float* __restrict__ Wp,
                            float* __restrict__ Bm, float* __restrict__ bias,
                            uint32_t* __restrict__ Whg2, uint32_t* __restrict__ Whc2,
                            uint32_t* __restrict__ Wp2) {
  int i = blockIdx.x * 256 + threadIdx.x;
  if (i < 196608) {                       // Bm: [256][768] combined input weights
    int k = i / 768, n = i % 768;
    Bm[i] = (n < GG) ? Wg[k * GG + n] : Wc[k * HH + (n - GG)];
    return;
  }
  int j = i - 196608;
  if (j < 768) {                          // bias[768]
    bias[j] = (j < GG) ? bg[j] : bc[j - GG];
    return;
  }
  int a = i - 197376;
  if (a < 65536) {                        // Whg2[k2*512+j]
    int k2 = a >> 9, jj = a & 511;
    Whg2[a] = pkbf(Wg[(DD + 2 * k2) * GG + jj], Wg[(DD + 2 * k2 + 1) * GG + jj]);
    return;
  }
  int c2 = i - 262912;
  if (c2 < 32768) {                       // Whc2[k2*256+j]
    int k2 = c2 >> 8, jj = c2 & 255;
    Whc2[c2] = pkbf(Wc[(DD + 2 * k2) * HH + jj], Wc[(DD + 2 * k2 + 1) * HH + jj]);
    return;
  }
  int p2 = i - 295680;
  if (p2 < 16384) {                       // Wp2[k2*128+j]
    int k2 = p2 >> 7, jj = p2 & 127;
    Wp2[p2] = pkbf(Wp[(2 * k2) * CC + jj], Wp[(2 * k2 + 1) * CC + jj]);
  }
}

// ---------- K1: input GEMM  gxc[65536][768] = x[65536][256] @ Bm[256][768] + bias ----------
__global__ __launch_bounds__(256) void gemm_in(const float* __restrict__ A,
                                               const float* __restrict__ Bm,
                                               const float* __restrict__ bias,
                                               float* __restrict__ Cm) {
  __shared__ __align__(16) float As[16][65];
  __shared__ __align__(16) float Bs[16][64];
  const int tidx = threadIdx.x;
  const int tx = tidx & 15;
  const int ty = tidx >> 4;
  const int m0 = blockIdx.y * 64;
  const int n0 = blockIdx.x * 64;
  float acc[4][4] = {};

  for (int k0 = 0; k0 < DD; k0 += 16) {
    {
      int r = tidx >> 2;
      int c = (tidx & 3) * 4;
      float4 av = *(const float4*)(A + (size_t)(m0 + r) * DD + k0 + c);
      As[c + 0][r] = av.x; As[c + 1][r] = av.y; As[c + 2][r] = av.z; As[c + 3][r] = av.w;
    }
    {
      int r = tidx >> 6;
      int cc = tidx & 63;
      #pragma unroll
      for (int i = 0; i < 4; i++)
        Bs[r + i * 4][cc] = Bm[(size_t)(k0 + r + i * 4) * 768 + n0 + cc];
    }
    __syncthreads();
    #pragma unroll
    for (int kk = 0; kk < 16; kk++) {
      float a[4], bb[4];
      #pragma unroll
      for (int i = 0; i < 4; i++) a[i] = As[kk][ty * 4 + i];
      #pragma unroll
      for (int jj = 0; jj < 4; jj++) bb[jj] = Bs[kk][tx * 4 + jj];
      #pragma unroll
      for (int i = 0; i < 4; i++)
        #pragma unroll
        for (int jj = 0; jj < 4; jj++)
          acc[i][jj] = fmaf(a[i], bb[jj], acc[i][jj]);
    }
    __syncthreads();
  }
  float4 bv = *(const float4*)&bias[n0 + tx * 4];
  #pragma unroll
  for (int i = 0; i < 4; i++) {
    int m = m0 + ty * 4 + i;
    float4 o;
    o.x = acc[i][0] + bv.x; o.y = acc[i][1] + bv.y;
    o.z = acc[i][2] + bv.z; o.w = acc[i][3] + bv.w;
    *(float4*)(Cm + (size_t)m * 768 + n0 + tx * 4) = o;
  }
}

// ---------- K2: scan with ALL recurrent weights resident in VGPRs ----------
// 512 threads, 2 waves/SIMD, 256-VGPR budget. Weight regs: 128 (gate) + 64 (cand,
// k-split x2) + 32 (proj, k-split x4) = 224 packed bf16x2. One block per batch elem.
__global__ __launch_bounds__(512, 2) void rnn_scan_reg(
    const float* __restrict__ gxc,
    const uint32_t* __restrict__ Whg2,
    const uint32_t* __restrict__ Whc2,
    const uint32_t* __restrict__ Wp2,
    const float* __restrict__ bproj,
    float* __restrict__ out) {
  __shared__ __align__(16) uint32_t s_h2[HH / 2];  // h packed bf16 k-pairs
  __shared__ __align__(16) float    s_hf[HH];      // h f32
  __shared__ __align__(16) uint32_t s_rh2[HH / 2]; // r*h packed bf16 k-pairs
  __shared__ __align__(16) float    s_u[HH];       // update gate
  __shared__ __align__(16) float    s_p[512];      // partials

  const int tid = threadIdx.x;
  const int b = blockIdx.x;
  const int jc = tid & 255, kh = tid >> 8;   // cand decomposition
  const int j3 = tid & 127, q = tid >> 7;    // proj decomposition

  // ---- load weights into registers (static indices only) ----
  uint32_t wg[128];
  #pragma unroll
  for (int i = 0; i < 128; i++) wg[i] = Whg2[i * 512 + tid];
  uint32_t wc[64];
  #pragma unroll
  for (int i = 0; i < 64; i++) wc[i] = Whc2[(kh * 64 + i) * 256 + jc];
  uint32_t wpj[32];
  #pragma unroll
  for (int i = 0; i < 32; i++) wpj[i] = Wp2[(q * 32 + i) * 128 + j3];

  if (tid < HH) s_hf[tid] = 0.f;
  if (tid < HH / 2) s_h2[tid] = 0u;

  const float* gx_b = gxc + (size_t)b * TT * 768;
  float* out_b = out + (size_t)b * TT * CC;

  float bp = (tid < CC) ? bproj[tid] : 0.f;
  float gv  = gx_b[tid];        // gate input, t=0
  float cxv = gx_b[GG + jc];    // cand input, t=0

  __syncthreads();

  for (int t = 0; t < TT; t++) {
    // prefetch next step's inputs (clamped at the end; consumed next iter)
    int tn = (t + 1 < TT) ? (t + 1) : (TT - 1);
    const float* gx_n = gx_b + (size_t)tn * 768;
    float gv_n  = gx_n[tid];
    float cx_n  = gx_n[GG + jc];

    // ---- phase 1: gate acc; thread tid owns gate output tid (full k) ----
    float acc = gv;
    #pragma unroll
    for (int k2 = 0; k2 < 128; k2 += 4) {
      uint4 hh = *(const uint4*)&s_h2[k2];
      acc = dot2bf(wg[k2 + 0], hh.x, acc);
      acc = dot2bf(wg[k2 + 1], hh.y, acc);
      acc = dot2bf(wg[k2 + 2], hh.z, acc);
      acc = dot2bf(wg[k2 + 3], hh.w, acc);
    }
    float g = 1.f / (1.f + __expf(-acc));
    if (tid < HH) {
      ((uint16_t*)s_rh2)[tid] = f2bf(g * s_hf[tid]);  // r*h, packed
    } else {
      s_u[tid - HH] = g;                              // u gate
    }
    __syncthreads();  // B: rh + u ready

    // ---- phase 2: cand partials; thread (jc, kh) owns half the k range ----
    {
      float acc2 = 0.f;
      #pragma unroll
      for (int i = 0; i < 64; i += 4) {
        uint4 rr = *(const uint4*)&s_rh2[kh * 64 + i];
        acc2 = dot2bf(wc[i + 0], rr.x, acc2);
        acc2 = dot2bf(wc[i + 1], rr.y, acc2);
        acc2 = dot2bf(wc[i + 2], rr.z, acc2);
        acc2 = dot2bf(wc[i + 3], rr.w, acc2);
      }
      s_p[kh * 256 + jc] = acc2;
    }
    __syncthreads();  // C: cand partials ready

    // ---- combine: c = tanh(cx + p0 + p1); h = u*h + (1-u)*c ----
    if (tid < HH) {
      float pre = cxv + s_p[tid] + s_p[256 + tid];
      float e = __expf(-2.f * fabsf(pre));
      float tm = (1.f - e) / (1.f + e);
      float c = copysignf(tm, pre);
      float u = s_u[tid];
      float hf = s_hf[tid];
      float hn = u * hf + (1.f - u) * c;
      s_hf[tid] = hn;
      ((uint16_t*)s_h2)[tid] = f2bf(hn);
    }
    __syncthreads();  // D: new h ready

    // ---- phase 3: proj partials; thread (j3, q) owns quarter k range ----
    {
      float acc3 = 0.f;
      #pragma unroll
      for (int i = 0; i < 32; i += 4) {
        uint4 hh = *(const uint4*)&s_h2[q * 32 + i];
        acc3 = dot2bf(wpj[i + 0], hh.x, acc3);
        acc3 = dot2bf(wpj[i + 1], hh.y, acc3);
        acc3 = dot2bf(wpj[i + 2], hh.z, acc3);
        acc3 = dot2bf(wpj[i + 3], hh.w, acc3);
      }
      s_p[q * 128 + j3] = acc3;
    }
    __syncthreads();  // E: proj partials ready

    if (tid < CC) {
      float pre = bp + s_p[tid] + s_p[128 + tid] + s_p[256 + tid] + s_p[384 + tid];
      out_b[(size_t)t * CC + tid] = 1.f / (1.f + __expf(-pre));
    }
    // output reads of s_p are fenced from next phase-2 writes by barrier B(t+1)

    gv = gv_n; cxv = cx_n;
  }
}

// ---------- launch ----------
extern "C" void kernel_launch(void* const* d_in, const int* in_sizes, int n_in,
                              void* d_out, int out_size, void* d_ws, size_t ws_size,
                              hipStream_t stream) {
  const float* x  = (const float*)d_in[0];
  const float* Wg = (const float*)d_in[1];
  const float* bg = (const float*)d_in[2];
  const float* Wc = (const float*)d_in[3];
  const float* bc = (const float*)d_in[4];
  const float* Wp = (const float*)d_in[5];
  const float* bp = (const float*)d_in[6];
  float* out = (float*)d_out;

  // workspace carve (bytes)
  char* w = (char*)d_ws;
  float*    gxc  = (float*)   (w);                  // 32*2048*768*4   = 201326592
  float*    Bm   = (float*)   (w + 201326592ull);   // 256*768*4       = 786432
  float*    bias = (float*)   (w + 202113024ull);   // 768*4           = 3072
  uint32_t* Whg2 = (uint32_t*)(w + 202116096ull);   // 128*512*4       = 262144
  uint32_t* Whc2 = (uint32_t*)(w + 202378240ull);   // 128*256*4       = 131072
  uint32_t* Wp2  = (uint32_t*)(w + 202509312ull);   // 128*128*4       = 65536

  prep_kernel<<<1219, 256, 0, stream>>>(Wg, bg, Wc, bc, Wp, Bm, bias, Whg2, Whc2, Wp2);
  gemm_in<<<dim3(12, 1024), 256, 0, stream>>>(x, Bm, bias, gxc);
  rnn_scan_reg<<<BB, 512, 0, stream>>>(gxc, Whg2, Whc2, Wp2, bp, out);
}